// Round 7
// baseline (484.821 us; speedup 1.0000x reference)
//
#include <hip/hip_runtime.h>
#include <hip/hip_bf16.h>

typedef __attribute__((ext_vector_type(4))) float floatx4;

static __device__ __forceinline__ unsigned short bf16_of(float f) {
    union { float f; unsigned u; } v; v.f = f;
    unsigned r = (v.u + 0x7FFF + ((v.u >> 16) & 1)) >> 16;   // RNE
    return (unsigned short)r;
}
static __device__ __forceinline__ float f32_of(unsigned short b) {
    union { float f; unsigned u; } v; v.u = ((unsigned)b) << 16;
    return v.f;
}

// ---------------------------------------------------------------------------
// Phase A (VALU GEMM, correctness-validated structure from R4):
//   Y[node][0:64]   = x[node] @ Wrel^T
//   Y[node][64:128] = x[node] @ Wroot^T      (Y stored bf16)
// x f32, W f32 (converted to bf16 in LDS). Block: 32 nodes, 256 threads.
// ---------------------------------------------------------------------------
__global__ __launch_bounds__(256) void gemm_simple(
    const float* __restrict__ X, const float* __restrict__ Wrel,
    const float* __restrict__ Wroot, unsigned short* __restrict__ Y, int N)
{
    __shared__ __align__(16) float          x_sh[32 * 132];   // 16.9 KB
    __shared__ __align__(16) unsigned short w_sh[128 * 132];  // 33.8 KB

    const int tid = threadIdx.x;
    const int m0  = blockIdx.x * 32;

    // Stage W (128 rows x 32 chunks of 4): 16 chunks/thread, f32 -> bf16
#pragma unroll
    for (int i = 0; i < 16; ++i) {
        int c   = tid + 256 * i;       // 0..4095
        int row = c >> 5;              // 0..127
        int f   = (c & 31) * 4;        // 0..124
        const float* src = (row < 64) ? (Wrel + row * 128 + f)
                                      : (Wroot + (row - 64) * 128 + f);
        floatx4 v = *(const floatx4*)src;
        unsigned short* d = &w_sh[row * 132 + f];
        d[0] = bf16_of(v[0]); d[1] = bf16_of(v[1]);
        d[2] = bf16_of(v[2]); d[3] = bf16_of(v[3]);
    }
    // Stage X (32 rows x 32 chunks of 4 floats): 4 chunks/thread
#pragma unroll
    for (int i = 0; i < 4; ++i) {
        int c    = tid + 256 * i;      // 0..1023
        int row  = c >> 5;             // 0..31
        int f    = (c & 31) * 4;
        int node = m0 + row;
        floatx4 v = {};
        if (node < N) v = *(const floatx4*)(X + (size_t)node * 128 + f);
        *(floatx4*)&x_sh[row * 132 + f] = v;
    }
    __syncthreads();

    const int nl   = tid >> 3;         // 0..31 local node
    const int oct  = tid & 7;          // col = oct + 8*j
    const int node = m0 + nl;
    if (node >= N) return;             // no barriers after this point

    const float* xr = &x_sh[nl * 132];
    float acc[16] = {};
    for (int k = 0; k < 128; k += 4) {
        floatx4 xv = *(const floatx4*)&xr[k];
#pragma unroll
        for (int j = 0; j < 16; ++j) {
            const unsigned short* wr = &w_sh[(oct + 8 * j) * 132 + k];
            acc[j] += xv[0] * f32_of(wr[0]) + xv[1] * f32_of(wr[1])
                    + xv[2] * f32_of(wr[2]) + xv[3] * f32_of(wr[3]);
        }
    }
#pragma unroll
    for (int j = 0; j < 16; ++j)
        Y[(size_t)node * 128 + oct + 8 * j] = bf16_of(acc[j]);
}

// ---------------------------------------------------------------------------
// Phase B: agg_t[dst][d] += Y_t[src][d], d in 0..63 (rel half). One wave/edge.
// ---------------------------------------------------------------------------
__global__ __launch_bounds__(256) void scatter_kernel(
    const int* __restrict__ e0, const int* __restrict__ e1,
    const unsigned short* __restrict__ Y0, const unsigned short* __restrict__ Y1,
    float* __restrict__ agg0, float* __restrict__ agg1, int E, int N)
{
    int w    = threadIdx.x >> 6;
    int lane = threadIdx.x & 63;
    int e    = blockIdx.x * 4 + w;
    if (e >= E) return;

    const int*            eidx = blockIdx.y ? e1 : e0;
    const unsigned short* Y    = blockIdx.y ? Y1 : Y0;
    float*                agg  = blockIdx.y ? agg1 : agg0;

    int src = eidx[e];
    int dst = eidx[E + e];
    if ((unsigned)src >= (unsigned)N || (unsigned)dst >= (unsigned)N) return;

    float v = f32_of(Y[(size_t)src * 128 + lane]);
    unsafeAtomicAdd(&agg[(size_t)dst * 64 + lane], v);
}

// ---------------------------------------------------------------------------
// Phase C: out[i] = dot(relu(agg0+Y0root+brel0), wfc[0:64])
//                 + dot(relu(agg1+Y1root+brel1), wfc[64:128]) + bfc
// FLOAT32 output (the R0-R6 saga's conclusion: d_out is f32).
// ---------------------------------------------------------------------------
__global__ __launch_bounds__(256) void final_kernel(
    const unsigned short* __restrict__ Y0, const unsigned short* __restrict__ Y1,
    const float* __restrict__ agg0, const float* __restrict__ agg1,
    const float* __restrict__ brel0, const float* __restrict__ brel1,
    const float* __restrict__ wfc, const float* __restrict__ bfc,
    float* __restrict__ out, int N)
{
    int w = threadIdx.x >> 6;
    int d = threadIdx.x & 63;
    int i = blockIdx.x * 4 + w;
    if (i >= N) return;

    float h0 = agg0[(size_t)i * 64 + d] + brel0[d] + f32_of(Y0[(size_t)i * 128 + 64 + d]);
    float h1 = agg1[(size_t)i * 64 + d] + brel1[d] + f32_of(Y1[(size_t)i * 128 + 64 + d]);
    h0 = fmaxf(h0, 0.f);
    h1 = fmaxf(h1, 0.f);
    float s = h0 * wfc[d] + h1 * wfc[64 + d];

#pragma unroll
    for (int m = 32; m > 0; m >>= 1) s += __shfl_xor(s, m, 64);

    if (d == 0) out[i] = s + bfc[0];
}

// ---------------------------------------------------------------------------
extern "C" void kernel_launch(void* const* d_in, const int* in_sizes, int n_in,
                              void* d_out, int out_size, void* d_ws, size_t ws_size,
                              hipStream_t stream)
{
    const int N = in_sizes[0] / 128;   // 50000
    const int E = in_sizes[2] / 2;     // 600000

    const float* x0     = (const float*)d_in[0];
    const float* x1     = (const float*)d_in[1];
    const int*   e0     = (const int*)d_in[2];
    const int*   e1     = (const int*)d_in[3];
    const float* Wrel0  = (const float*)d_in[4];
    const float* brel0  = (const float*)d_in[5];
    const float* Wroot0 = (const float*)d_in[6];
    const float* Wrel1  = (const float*)d_in[7];
    const float* brel1  = (const float*)d_in[8];
    const float* Wroot1 = (const float*)d_in[9];
    const float* wfc    = (const float*)d_in[10];
    const float* bfc    = (const float*)d_in[11];

    float* out = (float*)d_out;

    // Workspace: Y0 bf16 [N*128] | Y1 bf16 [N*128] | agg0 f32 [N*64] | agg1 f32 [N*64]
    // Total: 51.2 MB
    unsigned short* Y0 = (unsigned short*)d_ws;
    unsigned short* Y1 = Y0 + (size_t)N * 128;
    float* agg0 = (float*)(Y1 + (size_t)N * 128);
    float* agg1 = agg0 + (size_t)N * 64;

    (void)hipMemsetAsync(agg0, 0, (size_t)N * 64 * 2 * sizeof(float), stream);

    dim3 gemm_grid((N + 31) / 32);
    gemm_simple<<<gemm_grid, 256, 0, stream>>>(x0, Wrel0, Wroot0, Y0, N);
    gemm_simple<<<gemm_grid, 256, 0, stream>>>(x1, Wrel1, Wroot1, Y1, N);

    dim3 scat_grid((E + 3) / 4, 2);
    scatter_kernel<<<scat_grid, 256, 0, stream>>>(e0, e1, Y0, Y1, agg0, agg1, E, N);

    dim3 fin_grid((N + 3) / 4);
    final_kernel<<<fin_grid, 256, 0, stream>>>(Y0, Y1, agg0, agg1,
                                               brel0, brel1, wfc, bfc, out, N);
}

// Round 8
// 330.519 us; speedup vs baseline: 1.4668x; 1.4668x over previous
//
#include <hip/hip_runtime.h>
#include <hip/hip_bf16.h>

typedef __attribute__((ext_vector_type(8))) short short8;
typedef __attribute__((ext_vector_type(4))) float floatx4;

static __device__ __forceinline__ unsigned short bf16_of(float f) {
    union { float f; unsigned u; } v; v.f = f;
    unsigned r = (v.u + 0x7FFF + ((v.u >> 16) & 1)) >> 16;   // RNE
    return (unsigned short)r;
}
static __device__ __forceinline__ float f32_of(unsigned short b) {
    union { float f; unsigned u; } v; v.u = ((unsigned)b) << 16;
    return v.f;
}

// ---------------------------------------------------------------------------
// Phase A: MFMA GEMM (structure numerically validated in R3 per R6 forensic).
// Y[node][0:64] = x @ Wrel^T ; Y[node][64:128] = x @ Wroot^T ; Y stored bf16.
// grid.y selects relation. 32 nodes/block, 4 waves; wave w -> cols w*32..+31.
// ---------------------------------------------------------------------------
__global__ __launch_bounds__(256) void gemm_mfma(
    const float* __restrict__ X0, const float* __restrict__ X1,
    const float* __restrict__ Wrel0, const float* __restrict__ Wroot0,
    const float* __restrict__ Wrel1, const float* __restrict__ Wroot1,
    unsigned short* __restrict__ Y0, unsigned short* __restrict__ Y1, int N)
{
    const float* X     = blockIdx.y ? X1 : X0;
    const float* Wrel  = blockIdx.y ? Wrel1 : Wrel0;
    const float* Wroot = blockIdx.y ? Wroot1 : Wroot0;
    unsigned short* Y  = blockIdx.y ? Y1 : Y0;

    __shared__ __align__(16) short x_sh[32 * 136];
    __shared__ __align__(16) short w_sh[128 * 136];

    const int tid = threadIdx.x;
    const int m0  = blockIdx.x * 32;

    // Stage W (128 rows x 32 chunks of 4 floats) -> bf16
#pragma unroll
    for (int i = 0; i < 16; ++i) {
        int c   = tid + 256 * i;
        int row = c >> 5;
        int f   = (c & 31) * 4;
        const float* src = (row < 64) ? (Wrel + row * 128 + f)
                                      : (Wroot + (row - 64) * 128 + f);
        floatx4 v = *(const floatx4*)src;
        short* d = &w_sh[row * 136 + f];
        d[0] = (short)bf16_of(v[0]); d[1] = (short)bf16_of(v[1]);
        d[2] = (short)bf16_of(v[2]); d[3] = (short)bf16_of(v[3]);
    }
    // Stage X tile (32 rows) -> bf16, zero-pad tail
#pragma unroll
    for (int i = 0; i < 4; ++i) {
        int c    = tid + 256 * i;
        int row  = c >> 5;
        int f    = (c & 31) * 4;
        int node = m0 + row;
        floatx4 v = {};
        if (node < N) v = *(const floatx4*)(X + (size_t)node * 128 + f);
        short* d = &x_sh[row * 136 + f];
        d[0] = (short)bf16_of(v[0]); d[1] = (short)bf16_of(v[1]);
        d[2] = (short)bf16_of(v[2]); d[3] = (short)bf16_of(v[3]);
    }
    __syncthreads();

    const int w    = tid >> 6;
    const int lane = tid & 63;
    const int q    = lane >> 4;
    const int r    = lane & 15;

    floatx4 acc[2][2] = {};
#pragma unroll
    for (int ko = 0; ko < 4; ++ko) {
        int kb = ko * 32 + q * 8;
        short8 a0 = *(const short8*)&x_sh[(r) * 136 + kb];
        short8 a1 = *(const short8*)&x_sh[(16 + r) * 136 + kb];
        short8 b0 = *(const short8*)&w_sh[(w * 32 + r) * 136 + kb];
        short8 b1 = *(const short8*)&w_sh[(w * 32 + 16 + r) * 136 + kb];
        acc[0][0] = __builtin_amdgcn_mfma_f32_16x16x32_bf16(a0, b0, acc[0][0], 0, 0, 0);
        acc[0][1] = __builtin_amdgcn_mfma_f32_16x16x32_bf16(a0, b1, acc[0][1], 0, 0, 0);
        acc[1][0] = __builtin_amdgcn_mfma_f32_16x16x32_bf16(a1, b0, acc[1][0], 0, 0, 0);
        acc[1][1] = __builtin_amdgcn_mfma_f32_16x16x32_bf16(a1, b1, acc[1][1], 0, 0, 0);
    }

    // C/D: col = lane&15, row = (lane>>4)*4 + reg
#pragma unroll
    for (int mt = 0; mt < 2; ++mt)
#pragma unroll
        for (int nt = 0; nt < 2; ++nt) {
            int col = w * 32 + nt * 16 + r;
#pragma unroll
            for (int reg = 0; reg < 4; ++reg) {
                int node = m0 + mt * 16 + q * 4 + reg;
                if (node < N)
                    Y[(size_t)node * 128 + col] = bf16_of(acc[mt][nt][reg]);
            }
        }
}

// ---------------------------------------------------------------------------
// CSR build. K1: histogram of dst. grid.y = relation.
// ---------------------------------------------------------------------------
__global__ __launch_bounds__(256) void hist_kernel(
    const int* __restrict__ e0, const int* __restrict__ e1,
    int* __restrict__ deg0, int* __restrict__ deg1, int E, int N)
{
    const int* e  = blockIdx.y ? e1 : e0;
    int* deg      = blockIdx.y ? deg1 : deg0;
    int i = blockIdx.x * 256 + threadIdx.x;
    if (i >= E) return;
    int dst = e[E + i];
    if ((unsigned)dst < (unsigned)N) atomicAdd(&deg[dst], 1);
}

// K2: per-block (1024 items) exclusive scan of deg into rs; block sums out.
__global__ __launch_bounds__(256) void scan1_kernel(
    const int* __restrict__ deg0, const int* __restrict__ deg1,
    int* __restrict__ rs0, int* __restrict__ rs1,
    int* __restrict__ bsum, int N)
{
    const int* deg = blockIdx.y ? deg1 : deg0;
    int* rs        = blockIdx.y ? rs1 : rs0;

    __shared__ int sc[256];
    int t    = threadIdx.x;
    int base = blockIdx.x * 1024 + t * 4;

    int v[4]; int s = 0;
#pragma unroll
    for (int k = 0; k < 4; ++k) {
        v[k] = (base + k < N) ? deg[base + k] : 0;
        s += v[k];
    }
    sc[t] = s;
    __syncthreads();
    for (int off = 1; off < 256; off <<= 1) {
        int x = (t >= off) ? sc[t - off] : 0;
        __syncthreads();
        sc[t] += x;
        __syncthreads();
    }
    int run = sc[t] - s;   // exclusive across threads
#pragma unroll
    for (int k = 0; k < 4; ++k) {
        if (base + k < N) rs[base + k] = run;
        run += v[k];
    }
    if (t == 255) bsum[blockIdx.y * 64 + blockIdx.x] = sc[255];
}

// K3: scan the block sums (49 per relation) — trivial serial per relation.
__global__ void scan2_kernel(int* __restrict__ bsum, int nblk)
{
    int rel = threadIdx.x;
    if (rel >= 2) return;
    int run = 0;
    for (int b = 0; b < nblk; ++b) {
        int t = bsum[rel * 64 + b];
        bsum[rel * 64 + b] = run;
        run += t;
    }
}

// K4: add block offsets; init cursors.
__global__ __launch_bounds__(256) void scan3_kernel(
    int* __restrict__ rs0, int* __restrict__ rs1,
    int* __restrict__ cur0, int* __restrict__ cur1,
    const int* __restrict__ bsum, int N)
{
    int* rs  = blockIdx.y ? rs1 : rs0;
    int* cur = blockIdx.y ? cur1 : cur0;
    int i = blockIdx.x * 256 + threadIdx.x;
    if (i >= N) return;
    int v = rs[i] + bsum[blockIdx.y * 64 + (i >> 10)];
    rs[i] = v;
    cur[i] = v;
}

// K5: fill CSR src lists via cursors.
__global__ __launch_bounds__(256) void fill_kernel(
    const int* __restrict__ e0, const int* __restrict__ e1,
    int* __restrict__ cur0, int* __restrict__ cur1,
    int* __restrict__ csr0, int* __restrict__ csr1, int E, int N)
{
    const int* e = blockIdx.y ? e1 : e0;
    int* cur     = blockIdx.y ? cur1 : cur0;
    int* csr     = blockIdx.y ? csr1 : csr0;
    int i = blockIdx.x * 256 + threadIdx.x;
    if (i >= E) return;
    int src = e[i];
    int dst = e[E + i];
    if ((unsigned)dst >= (unsigned)N) return;
    int pos = atomicAdd(&cur[dst], 1);
    csr[pos] = ((unsigned)src < (unsigned)N) ? src : 0;
}

// ---------------------------------------------------------------------------
// Phase B+C fused: per node i (one wave), pull-gather both relations'
// neighbor sums in registers, then relu + FC + bias, f32 out. No atomics.
// ---------------------------------------------------------------------------
__global__ __launch_bounds__(256) void gather_final(
    const unsigned short* __restrict__ Y0, const unsigned short* __restrict__ Y1,
    const int* __restrict__ rs0, const int* __restrict__ deg0, const int* __restrict__ csr0,
    const int* __restrict__ rs1, const int* __restrict__ deg1, const int* __restrict__ csr1,
    const float* __restrict__ brel0, const float* __restrict__ brel1,
    const float* __restrict__ wfc, const float* __restrict__ bfc,
    float* __restrict__ out, int N)
{
    int wv   = threadIdx.x >> 6;
    int lane = threadIdx.x & 63;
    int i    = blockIdx.x * 4 + wv;
    if (i >= N) return;

    float a0 = 0.f, a1 = 0.f;

#pragma unroll
    for (int rel = 0; rel < 2; ++rel) {
        const int* rs  = rel ? rs1 : rs0;
        const int* deg = rel ? deg1 : deg0;
        const int* csr = rel ? csr1 : csr0;
        const unsigned short* Y = rel ? Y1 : Y0;
        float a = 0.f;
        int start = rs[i], d = deg[i];
        for (int j0 = 0; j0 < d; j0 += 64) {
            int nb  = min(64, d - j0);
            int idx = (j0 + lane < d) ? csr[start + j0 + lane] : 0;
            int j = 0;
            for (; j + 1 < nb; j += 2) {       // 2 loads in flight
                int s0 = __shfl(idx, j, 64);
                int s1 = __shfl(idx, j + 1, 64);
                float v0 = f32_of(Y[(size_t)s0 * 128 + lane]);
                float v1 = f32_of(Y[(size_t)s1 * 128 + lane]);
                a += v0 + v1;
            }
            if (j < nb) {
                int s0 = __shfl(idx, j, 64);
                a += f32_of(Y[(size_t)s0 * 128 + lane]);
            }
        }
        if (rel) a1 = a; else a0 = a;
    }

    float h0 = fmaxf(a0 + brel0[lane] + f32_of(Y0[(size_t)i * 128 + 64 + lane]), 0.f);
    float h1 = fmaxf(a1 + brel1[lane] + f32_of(Y1[(size_t)i * 128 + 64 + lane]), 0.f);
    float s  = h0 * wfc[lane] + h1 * wfc[64 + lane];

#pragma unroll
    for (int m = 32; m > 0; m >>= 1) s += __shfl_xor(s, m, 64);

    if (lane == 0) out[i] = s + bfc[0];
}

// ---------------------------------------------------------------------------
extern "C" void kernel_launch(void* const* d_in, const int* in_sizes, int n_in,
                              void* d_out, int out_size, void* d_ws, size_t ws_size,
                              hipStream_t stream)
{
    const int N = in_sizes[0] / 128;   // 50000
    const int E = in_sizes[2] / 2;     // 600000

    const float* x0     = (const float*)d_in[0];
    const float* x1     = (const float*)d_in[1];
    const int*   e0     = (const int*)d_in[2];
    const int*   e1     = (const int*)d_in[3];
    const float* Wrel0  = (const float*)d_in[4];
    const float* brel0  = (const float*)d_in[5];
    const float* Wroot0 = (const float*)d_in[6];
    const float* Wrel1  = (const float*)d_in[7];
    const float* brel1  = (const float*)d_in[8];
    const float* Wroot1 = (const float*)d_in[9];
    const float* wfc    = (const float*)d_in[10];
    const float* bfc    = (const float*)d_in[11];
    float* out = (float*)d_out;

    // Workspace: Y0,Y1 bf16 [N*128 each] | deg0,deg1 | rs0,rs1 | cur0,cur1
    //            | csr0,csr1 [E each] | bsum[128]     (~31 MB total)
    unsigned short* Y0 = (unsigned short*)d_ws;
    unsigned short* Y1 = Y0 + (size_t)N * 128;
    int* deg0 = (int*)(Y1 + (size_t)N * 128);
    int* deg1 = deg0 + N;
    int* rs0  = deg1 + N;
    int* rs1  = rs0 + N;
    int* cur0 = rs1 + N;
    int* cur1 = cur0 + N;
    int* csr0 = cur1 + N;
    int* csr1 = csr0 + E;
    int* bsum = csr1 + E;

    (void)hipMemsetAsync(deg0, 0, (size_t)2 * N * sizeof(int), stream);

    const int nblk = (N + 1023) / 1024;          // 49

    dim3 gemm_grid((N + 31) / 32, 2);
    gemm_mfma<<<gemm_grid, 256, 0, stream>>>(x0, x1, Wrel0, Wroot0,
                                             Wrel1, Wroot1, Y0, Y1, N);

    dim3 eg((E + 255) / 256, 2);
    hist_kernel<<<eg, 256, 0, stream>>>(e0, e1, deg0, deg1, E, N);

    dim3 sg(nblk, 2);
    scan1_kernel<<<sg, 256, 0, stream>>>(deg0, deg1, rs0, rs1, bsum, N);
    scan2_kernel<<<1, 64, 0, stream>>>(bsum, nblk);
    dim3 ng((N + 255) / 256, 2);
    scan3_kernel<<<ng, 256, 0, stream>>>(rs0, rs1, cur0, cur1, bsum, N);

    fill_kernel<<<eg, 256, 0, stream>>>(e0, e1, cur0, cur1, csr0, csr1, E, N);

    gather_final<<<(N + 3) / 4, 256, 0, stream>>>(
        Y0, Y1, rs0, deg0, csr0, rs1, deg1, csr1,
        brel0, brel1, wfc, bfc, out, N);
}